// Round 10
// baseline (221.087 us; speedup 1.0000x reference)
//
#include <hip/hip_runtime.h>

#define F_DIMC 64
#define K_DIMC 16
#define NGRAPH 64
#define NXCD 8
#define ADJ_SPLIT 24
#define SX_SPLIT 8
#define NB_SEL 400                         // N/256
#define NB_HIST 256
#define FUSE_BLOCKS 2048                   // per XCD: 192 adj + 64 sx, 3:1 interleave
#define ADJ_OFF (NGRAPH * K_DIMC * F_DIMC)
#define LOSS_OFF (ADJ_OFF + NGRAPH * K_DIMC * K_DIMC)

// ---------------- workspace layout (bytes) ----------------
// zeroed each call: [0, 394496)
//   [0,256)          hist (int[64])
//   [256,512)        cursor (int[64])
//   [512,768)        den (float[64])
//   [768,1024)       donecnt (int) + pad
//   [1024,66560)     dense_raw (float[64*256])
//   [66560,132096)   ssbuf (float[64*256])
//   [132096,394240)  sxbuf (float[64*1024])
//   [394240,394496)  loss (float[2]) + pad
// not zeroed:
//   [394496,394752)    offsets (int[64])
//   [394752,6948352)   sel (float[N*16])
//   [6948352,13501952) sorted (uint2[E])

__global__ __launch_bounds__(256) void k_hist(const int* __restrict__ row,
                                              int* __restrict__ hist,
                                              int E4, int perG) {
    __shared__ int lh[NGRAPH];
    int t = threadIdx.x;
    if (t < NGRAPH) lh[t] = 0;
    __syncthreads();
    for (int e4 = blockIdx.x * 256 + t; e4 < E4; e4 += NB_HIST * 256) {
        int4 r4 = ((const int4*)row)[e4];
        atomicAdd(&lh[r4.x / perG], 1);
        atomicAdd(&lh[r4.y / perG], 1);
        atomicAdd(&lh[r4.z / perG], 1);
        atomicAdd(&lh[r4.w / perG], 1);
    }
    __syncthreads();
    if (t < NGRAPH) {
        int c = lh[t];
        if (c) atomicAdd(&hist[t], c);
    }
}

// ---- fused: selection (blocks [0,NB_SEL)) || counting-sort scatter (rest) ----
// sel is independent of hist; scatter needs hist (prior kernel) -> overlap legal.
__global__ __launch_bounds__(256) void k_sel_scatter(const float* __restrict__ node_attr,
                                                     const float* __restrict__ W,
                                                     const float* __restrict__ bias,
                                                     const int* __restrict__ row,
                                                     const int* __restrict__ col,
                                                     const int* __restrict__ hist,
                                                     int* __restrict__ cursor,
                                                     int* __restrict__ offsets,
                                                     float* __restrict__ sel,
                                                     uint2* __restrict__ sorted,
                                                     int N, int E, int perG) {
    int t = threadIdx.x;
    if (blockIdx.x < NB_SEL) {
        __shared__ float sW[K_DIMC][F_DIMC];
        __shared__ float sb[K_DIMC];
        for (int idx = t; idx < F_DIMC * K_DIMC; idx += 256) {
            int f = idx / K_DIMC, k = idx % K_DIMC;
            sW[k][f] = W[idx];
        }
        if (t < K_DIMC) sb[t] = bias[t];
        __syncthreads();
        int n = blockIdx.x * 256 + t;
        if (n >= N) return;

        const float4* xr = (const float4*)(node_attr + (size_t)n * F_DIMC);
        float4 x[F_DIMC / 4];
#pragma unroll
        for (int f4 = 0; f4 < F_DIMC / 4; ++f4) x[f4] = xr[f4];

        float logits[K_DIMC];
#pragma unroll
        for (int k = 0; k < K_DIMC; ++k) {
            const float4* wk = (const float4*)&sW[k][0];
            float acc = sb[k];
#pragma unroll
            for (int f4 = 0; f4 < F_DIMC / 4; ++f4) {
                float4 w = wk[f4];
                acc += x[f4].x * w.x + x[f4].y * w.y + x[f4].z * w.z + x[f4].w * w.w;
            }
            logits[k] = acc;
        }
        float m = logits[0];
#pragma unroll
        for (int k = 1; k < K_DIMC; ++k) m = fmaxf(m, logits[k]);
        float sum = 0.f;
#pragma unroll
        for (int k = 0; k < K_DIMC; ++k) {
            float e = __expf(logits[k] - m);
            logits[k] = e;
            sum += e;
        }
        float inv = 1.f / sum;
        float4* sd = (float4*)(sel + (size_t)n * K_DIMC);
#pragma unroll
        for (int k4 = 0; k4 < K_DIMC / 4; ++k4) {
            float4 v;
            v.x = logits[4 * k4 + 0] * inv;
            v.y = logits[4 * k4 + 1] * inv;
            v.z = logits[4 * k4 + 2] * inv;
            v.w = logits[4 * k4 + 3] * inv;
            sd[k4] = v;
        }
    } else {
        __shared__ int offs[NGRAPH];
        __shared__ int lcnt[NGRAPH];
        __shared__ int lbase[NGRAPH];
        if (t < 64) {
            int v = hist[t];
            int sum = v;
#pragma unroll
            for (int d = 1; d < 64; d <<= 1) {
                int o = __shfl_up(sum, d);
                if (t >= d) sum += o;
            }
            offs[t] = sum - v;
            lcnt[t] = 0;
            if (blockIdx.x == NB_SEL) offsets[t] = sum - v;
        }
        __syncthreads();
        int e = (blockIdx.x - NB_SEL) * 256 + t;
        int r = 0, c = 0, g = 0, lpos = 0;
        bool valid = e < E;
        if (valid) {
            r = row[e];
            c = col[e];
            g = r / perG;
            lpos = atomicAdd(&lcnt[g], 1);
        }
        __syncthreads();
        if (t < NGRAPH) {
            int cnt = lcnt[t];
            if (cnt) lbase[t] = offs[t] + atomicAdd(&cursor[t], cnt);
        }
        __syncthreads();
        if (valid) {
            sorted[(size_t)lbase[g] + lpos] = make_uint2((unsigned)r, (unsigned)c);
        }
    }
}

// ---- fused adj || SX, EXACTLY 2048 blocks (one full residency wave, no tail) ----
// b -> XCD x=b&7, m=b>>3 (0..255/XCD): m%4==3 -> SX (64/XCD), else adj (192/XCD).
// adj: batched edge loads with NEXT-BATCH PREFETCH; uniform readlane broadcast;
// den free via per-lane a^2 (sum over 64 lanes = 4*q[row_e]).
__global__ __launch_bounds__(256) void k_adj_sx(const uint2* __restrict__ sorted,
                                                const int* __restrict__ offsets,
                                                const int* __restrict__ hist,
                                                const float* __restrict__ sel,
                                                const float* __restrict__ x,
                                                float* __restrict__ dense_raw,
                                                float* __restrict__ ssbuf,
                                                float* __restrict__ sxbuf,
                                                float* __restrict__ den,
                                                int perG) {
    __shared__ union {
        struct { float lacc[4][256]; float qred[4]; } a;
        struct { float lsx[4][K_DIMC * F_DIMC]; float lss[4][256]; } s;
    } u;                                   // 20KB -> 8 blocks/CU
    int b = blockIdx.x;
    int t = threadIdx.x;
    int wid = t >> 6;
    int lane = t & 63;
    int xcd = b & (NXCD - 1);
    int m = b >> 3;                        // 0..255 within this XCD
    if ((m & 3) != 3) {
        // ---------------- adj role ----------------
        int a_idx = (m >> 2) * 3 + (m & 3);          // 0..191
        int g = xcd * (NGRAPH / NXCD) + a_idx / ADJ_SPLIT;
        int split = a_idx % ADJ_SPLIT;

        int start = offsets[g];
        int cnt = hist[g];
        int wavesPerGraph = ADJ_SPLIT * 4;           // 96
        int wseq = split * 4 + wid;
        int i = lane >> 2;
        int j0 = (lane & 3) * 4;

        int chunk = (cnt + wavesPerGraph - 1) / wavesPerGraph;
        int myStart = start + wseq * chunk;
        int myEnd = start + cnt;
        if (myStart + chunk < myEnd) myEnd = myStart + chunk;

        float ax = 0.f, ay = 0.f, az = 0.f, aw = 0.f, qacc = 0.f;
        if (myStart < myEnd) {
            int nb0 = myEnd - myStart;
            if (nb0 > 64) nb0 = 64;
            uint2 pr = sorted[myStart + (lane < nb0 ? lane : nb0 - 1)];
            for (int r0 = myStart; r0 < myEnd; r0 += 64) {
                int nb = myEnd - r0;
                if (nb > 64) nb = 64;
                uint2 cur = pr;
                int nxt = r0 + 64;
                if (nxt < myEnd) {        // prefetch next batch during compute
                    int nb2 = myEnd - nxt;
                    if (nb2 > 64) nb2 = 64;
                    pr = sorted[nxt + (lane < nb2 ? lane : nb2 - 1)];
                }
                int rx = (int)cur.x * K_DIMC;
                int cx = (int)cur.y * K_DIMC;
#pragma unroll 16
                for (int ee = 0; ee < nb; ++ee) {
                    int rb = __builtin_amdgcn_readlane(rx, ee);
                    int cb = __builtin_amdgcn_readlane(cx, ee);
                    float a = sel[rb + i];
                    float4 bv = *(const float4*)(sel + cb + j0);
                    ax = fmaf(a, bv.x, ax);
                    ay = fmaf(a, bv.y, ay);
                    az = fmaf(a, bv.z, az);
                    aw = fmaf(a, bv.w, aw);
                    qacc = fmaf(a, a, qacc);
                }
            }
        }
        *(float4*)&u.a.lacc[wid][i * K_DIMC + j0] = make_float4(ax, ay, az, aw);
#pragma unroll
        for (int off = 32; off > 0; off >>= 1) qacc += __shfl_down(qacc, off);
        if (lane == 0) u.a.qred[wid] = qacc;
        __syncthreads();
        float s = u.a.lacc[0][t] + u.a.lacc[1][t] + u.a.lacc[2][t] + u.a.lacc[3][t];
        atomicAdd(dense_raw + g * 256 + t, s);
        if (t == 0) {
            float qs = (u.a.qred[0] + u.a.qred[1] + u.a.qred[2] + u.a.qred[3]) * 0.25f;
            atomicAdd(den + g, qs);
        }
    } else {
        // ---------------- SX/SS role ----------------
        int sidx = m >> 2;                 // 0..63
        int g = xcd * (NGRAPH / NXCD) + (sidx >> 3);
        int split = sidx & (SX_SPLIT - 1);
        int wslot = split * 4 + wid;       // 0..31
        int k = lane >> 2;
        int sub = lane & 3;
        int f0 = sub * 16;
        int j0 = sub * 4;
        float accss[4] = {0.f, 0.f, 0.f, 0.f};
        float accsx[16];
#pragma unroll
        for (int j = 0; j < 16; ++j) accsx[j] = 0.f;
        size_t base = (size_t)g * perG;
#pragma unroll 2
        for (int nn = wslot; nn < perG; nn += SX_SPLIT * 4) {
            size_t node = base + nn;
            float a = sel[node * K_DIMC + k];
            float4 s4 = *(const float4*)(sel + node * K_DIMC + j0);
            accss[0] += a * s4.x;
            accss[1] += a * s4.y;
            accss[2] += a * s4.z;
            accss[3] += a * s4.w;
            const float4* xv = (const float4*)(x + node * F_DIMC + f0);
#pragma unroll
            for (int j = 0; j < 4; ++j) {
                float4 v = xv[j];
                accsx[4 * j + 0] += a * v.x;
                accsx[4 * j + 1] += a * v.y;
                accsx[4 * j + 2] += a * v.z;
                accsx[4 * j + 3] += a * v.w;
            }
        }
#pragma unroll
        for (int j4 = 0; j4 < 4; ++j4) {
            *(float4*)&u.s.lsx[wid][k * F_DIMC + f0 + 4 * j4] =
                make_float4(accsx[4 * j4], accsx[4 * j4 + 1], accsx[4 * j4 + 2], accsx[4 * j4 + 3]);
        }
        *(float4*)&u.s.lss[wid][k * K_DIMC + j0] = make_float4(accss[0], accss[1], accss[2], accss[3]);
        __syncthreads();
        for (int c2 = t; c2 < K_DIMC * F_DIMC; c2 += 256) {
            float s = u.s.lsx[0][c2] + u.s.lsx[1][c2] + u.s.lsx[2][c2] + u.s.lsx[3][c2];
            atomicAdd(sxbuf + (size_t)g * (K_DIMC * F_DIMC) + c2, s);
        }
        {
            float s = u.s.lss[0][t] + u.s.lss[1][t] + u.s.lss[2][t] + u.s.lss[3][t];
            atomicAdd(ssbuf + g * 256 + t, s);
        }
    }
}

// ---- finalize: normalize adj, copy SX to out, losses via ws + last-block write ----
__global__ __launch_bounds__(256) void k_fin(const float* __restrict__ dense_raw,
                                             const float* __restrict__ ssbuf,
                                             const float* __restrict__ sxbuf,
                                             const float* __restrict__ den,
                                             float* __restrict__ lossws,
                                             int* __restrict__ donecnt,
                                             float* __restrict__ out) {
    int g = blockIdx.x;
    int c = threadIdx.x;
    int k = c >> 4, j = c & 15;
    int lane = threadIdx.x & 63;
    int wid = threadIdx.x >> 6;

    ((float4*)(out + (size_t)g * (K_DIMC * F_DIMC)))[c] =
        ((const float4*)(sxbuf + (size_t)g * (K_DIMC * F_DIMC)))[c];

    float a = dense_raw[g * 256 + c];
    float s = a;
    s += __shfl_xor(s, 1);
    s += __shfl_xor(s, 2);
    s += __shfl_xor(s, 4);
    s += __shfl_xor(s, 8);
    __shared__ float dvrow[K_DIMC];
    if (j == 0) dvrow[k] = sqrtf(s) + 1e-15f;
    __syncthreads();
    float v = a / (dvrow[k] * dvrow[j]);
    out[ADJ_OFF + g * 256 + c] = v;

    float ss = ssbuf[g * 256 + c];
    float tt = (k == j) ? v : 0.f;
    float n2 = ss * ss;
#pragma unroll
    for (int off = 32; off > 0; off >>= 1) {
        tt += __shfl_down(tt, off);
        n2 += __shfl_down(n2, off);
    }
    __shared__ float redt[4], redn[4];
    if (lane == 0) { redt[wid] = tt; redn[wid] = n2; }
    __syncthreads();
    float tr = redt[0] + redt[1] + redt[2] + redt[3];
    float nrm2 = redn[0] + redn[1] + redn[2] + redn[3];
    float invn = 1.f / sqrtf(nrm2);
    float d = ss * invn - ((k == j) ? 0.25f : 0.f);
    float o2 = d * d;
#pragma unroll
    for (int off = 32; off > 0; off >>= 1) o2 += __shfl_down(o2, off);
    __shared__ float redo[4];
    if (lane == 0) redo[wid] = o2;
    __syncthreads();
    if (threadIdx.x == 0) {
        float osum = redo[0] + redo[1] + redo[2] + redo[3];
        float og = sqrtf(osum);
        float mterm = -(tr / den[g]);
        atomicAdd(lossws + 0, mterm * (1.f / NGRAPH));
        atomicAdd(lossws + 1, og * (1.f / NGRAPH));
        __threadfence();
        int old = atomicAdd(donecnt, 1);
        if (old == NGRAPH - 1) {
            float l0 = atomicAdd(lossws + 0, 0.f);
            float l1 = atomicAdd(lossws + 1, 0.f);
            out[LOSS_OFF + 0] = l0;
            out[LOSS_OFF + 1] = l1;
        }
    }
}

extern "C" void kernel_launch(void* const* d_in, const int* in_sizes, int n_in,
                              void* d_out, int out_size, void* d_ws, size_t ws_size,
                              hipStream_t stream) {
    const float* node_attr = (const float*)d_in[0];
    const float* W = (const float*)d_in[1];
    const float* bias = (const float*)d_in[2];
    const int* edge_index = (const int*)d_in[3];
    int N = in_sizes[0] / F_DIMC;
    int E = in_sizes[3] / 2;
    int perG = N / NGRAPH;
    const int* row = edge_index;
    const int* col = edge_index + E;
    float* out = (float*)d_out;
    char* ws = (char*)d_ws;

    int* hist = (int*)(ws + 0);
    int* cursor = (int*)(ws + 256);
    float* den = (float*)(ws + 512);
    int* donecnt = (int*)(ws + 768);
    float* dense_raw = (float*)(ws + 1024);
    float* ssbuf = (float*)(ws + 66560);
    float* sxbuf = (float*)(ws + 132096);
    float* lossws = (float*)(ws + 394240);
    int* offsets = (int*)(ws + 394496);
    float* sel = (float*)(ws + 394752);
    uint2* sorted = (uint2*)(ws + 6948352);

    hipMemsetAsync(ws, 0, 394496, stream);

    k_hist<<<NB_HIST, 256, 0, stream>>>(row, hist, E / 4, perG);
    k_sel_scatter<<<NB_SEL + (E + 255) / 256, 256, 0, stream>>>(node_attr, W, bias, row, col,
                                                                hist, cursor, offsets, sel,
                                                                sorted, N, E, perG);
    k_adj_sx<<<FUSE_BLOCKS, 256, 0, stream>>>(sorted, offsets, hist, sel, node_attr,
                                              dense_raw, ssbuf, sxbuf, den, perG);
    k_fin<<<NGRAPH, 256, 0, stream>>>(dense_raw, ssbuf, sxbuf, den, lossws, donecnt, out);
}

// Round 11
// 151.899 us; speedup vs baseline: 1.4555x; 1.4555x over previous
//
#include <hip/hip_runtime.h>

#define F_DIMC 64
#define K_DIMC 16
#define NGRAPH 64
#define NXCD 8
#define ADJ_SPLIT 32
#define SX_WAVES 8
#define SX_SPLIT 8
#define NB_SEL 400                         // N/256
#define NB_HIST 256
#define ADJ_OFF (NGRAPH * K_DIMC * F_DIMC)
#define LOSS_OFF (ADJ_OFF + NGRAPH * K_DIMC * K_DIMC)

// ---------------- workspace layout (bytes) ----------------
// zeroed each call: [0, 394496)
//   [0,256)          hist (int[64])
//   [256,512)        cursor (int[64])
//   [512,768)        den (float[64])
//   [768,1024)       donecnt (int) + pad
//   [1024,66560)     dense_raw (float[64*256])
//   [66560,132096)   ssbuf (float[64*256])
//   [132096,394240)  sxbuf (float[64*1024])
//   [394240,394496)  loss (float[2]) + pad
// not zeroed:
//   [394496,394752)    offsets (int[64])
//   [394752,6948352)   sel (float[N*16])
//   [6948352,13501952) sorted (uint2[E])

__global__ __launch_bounds__(256) void k_hist(const int* __restrict__ row,
                                              int* __restrict__ hist,
                                              int E4, int perG) {
    __shared__ int lh[NGRAPH];
    int t = threadIdx.x;
    if (t < NGRAPH) lh[t] = 0;
    __syncthreads();
    for (int e4 = blockIdx.x * 256 + t; e4 < E4; e4 += NB_HIST * 256) {
        int4 r4 = ((const int4*)row)[e4];
        atomicAdd(&lh[r4.x / perG], 1);
        atomicAdd(&lh[r4.y / perG], 1);
        atomicAdd(&lh[r4.z / perG], 1);
        atomicAdd(&lh[r4.w / perG], 1);
    }
    __syncthreads();
    if (t < NGRAPH) {
        int c = lh[t];
        if (c) atomicAdd(&hist[t], c);
    }
}

// ---- fused: selection (blocks [0,NB_SEL)) || counting-sort scatter (rest) ----
__global__ __launch_bounds__(256) void k_sel_scatter(const float* __restrict__ node_attr,
                                                     const float* __restrict__ W,
                                                     const float* __restrict__ bias,
                                                     const int* __restrict__ row,
                                                     const int* __restrict__ col,
                                                     const int* __restrict__ hist,
                                                     int* __restrict__ cursor,
                                                     int* __restrict__ offsets,
                                                     float* __restrict__ sel,
                                                     uint2* __restrict__ sorted,
                                                     int N, int E, int perG) {
    int t = threadIdx.x;
    if (blockIdx.x < NB_SEL) {
        __shared__ float sW[K_DIMC][F_DIMC];
        __shared__ float sb[K_DIMC];
        for (int idx = t; idx < F_DIMC * K_DIMC; idx += 256) {
            int f = idx / K_DIMC, k = idx % K_DIMC;
            sW[k][f] = W[idx];
        }
        if (t < K_DIMC) sb[t] = bias[t];
        __syncthreads();
        int n = blockIdx.x * 256 + t;
        if (n >= N) return;

        const float4* xr = (const float4*)(node_attr + (size_t)n * F_DIMC);
        float4 x[F_DIMC / 4];
#pragma unroll
        for (int f4 = 0; f4 < F_DIMC / 4; ++f4) x[f4] = xr[f4];

        float logits[K_DIMC];
#pragma unroll
        for (int k = 0; k < K_DIMC; ++k) {
            const float4* wk = (const float4*)&sW[k][0];
            float acc = sb[k];
#pragma unroll
            for (int f4 = 0; f4 < F_DIMC / 4; ++f4) {
                float4 w = wk[f4];
                acc += x[f4].x * w.x + x[f4].y * w.y + x[f4].z * w.z + x[f4].w * w.w;
            }
            logits[k] = acc;
        }
        float m = logits[0];
#pragma unroll
        for (int k = 1; k < K_DIMC; ++k) m = fmaxf(m, logits[k]);
        float sum = 0.f;
#pragma unroll
        for (int k = 0; k < K_DIMC; ++k) {
            float e = __expf(logits[k] - m);
            logits[k] = e;
            sum += e;
        }
        float inv = 1.f / sum;
        float4* sd = (float4*)(sel + (size_t)n * K_DIMC);
#pragma unroll
        for (int k4 = 0; k4 < K_DIMC / 4; ++k4) {
            float4 v;
            v.x = logits[4 * k4 + 0] * inv;
            v.y = logits[4 * k4 + 1] * inv;
            v.z = logits[4 * k4 + 2] * inv;
            v.w = logits[4 * k4 + 3] * inv;
            sd[k4] = v;
        }
    } else {
        __shared__ int offs[NGRAPH];
        __shared__ int lcnt[NGRAPH];
        __shared__ int lbase[NGRAPH];
        if (t < 64) {
            int v = hist[t];
            int sum = v;
#pragma unroll
            for (int d = 1; d < 64; d <<= 1) {
                int o = __shfl_up(sum, d);
                if (t >= d) sum += o;
            }
            offs[t] = sum - v;
            lcnt[t] = 0;
            if (blockIdx.x == NB_SEL) offsets[t] = sum - v;
        }
        __syncthreads();
        int e = (blockIdx.x - NB_SEL) * 256 + t;
        int r = 0, c = 0, g = 0, lpos = 0;
        bool valid = e < E;
        if (valid) {
            r = row[e];
            c = col[e];
            g = r / perG;
            lpos = atomicAdd(&lcnt[g], 1);
        }
        __syncthreads();
        if (t < NGRAPH) {
            int cnt = lcnt[t];
            if (cnt) lbase[t] = offs[t] + atomicAdd(&cursor[t], cnt);
        }
        __syncthreads();
        if (valid) {
            sorted[(size_t)lbase[g] + lpos] = make_uint2((unsigned)r, (unsigned)c);
        }
    }
}

// ---- adj standalone (round-6 structure + explicit 8-edge load batching) ----
// Flat 2048 blocks, XCD-swizzled (graph's 32 blocks on one XCD -> sel L2-resident).
// Per 64-edge batch: coalesced uint2 load; inner loop in 8-edge sub-batches:
// issue all 16 loads into named regs FIRST, then 40 FMAs -> ~16 outstanding
// loads per wave (vs ~4 when the compiler schedules a fused load+FMA chain).
// den free via per-lane a^2 (sum over 64 lanes = 4*q[row_e]).
__global__ __launch_bounds__(256) void k_adj(const uint2* __restrict__ sorted,
                                             const int* __restrict__ offsets,
                                             const int* __restrict__ hist,
                                             const float* __restrict__ sel,
                                             float* __restrict__ dense_raw,
                                             float* __restrict__ den) {
    int b = blockIdx.x;
    int xcd = b & (NXCD - 1);
    int idx = b >> 3;
    int g = xcd * (NGRAPH / NXCD) + (idx >> 5);
    int split = idx & (ADJ_SPLIT - 1);

    int start = offsets[g];
    int cnt = hist[g];
    int wavesPerGraph = ADJ_SPLIT * 4;        // 128
    int wid = threadIdx.x >> 6;
    int wseq = split * 4 + wid;
    int lane = threadIdx.x & 63;
    int i = lane >> 2;
    int j0 = (lane & 3) * 4;

    int chunk = (cnt + wavesPerGraph - 1) / wavesPerGraph;
    int myStart = start + wseq * chunk;
    int myEnd = start + cnt;
    if (myStart + chunk < myEnd) myEnd = myStart + chunk;

    float ax = 0.f, ay = 0.f, az = 0.f, aw = 0.f, qacc = 0.f;
    for (int r0 = myStart; r0 < myEnd; r0 += 64) {
        int nb = myEnd - r0;
        if (nb > 64) nb = 64;
        uint2 pr = sorted[r0 + (lane < nb ? lane : nb - 1)];
        int rx = (int)pr.x * K_DIMC;
        int cx = (int)pr.y * K_DIMC;
        int ee = 0;
        for (; ee + 8 <= nb; ee += 8) {
            float a_[8];
            float4 b_[8];
#pragma unroll
            for (int u = 0; u < 8; ++u) {
                int rb = __builtin_amdgcn_readlane(rx, ee + u);
                int cb = __builtin_amdgcn_readlane(cx, ee + u);
                a_[u] = sel[rb + i];
                b_[u] = *(const float4*)(sel + cb + j0);
            }
#pragma unroll
            for (int u = 0; u < 8; ++u) {
                ax = fmaf(a_[u], b_[u].x, ax);
                ay = fmaf(a_[u], b_[u].y, ay);
                az = fmaf(a_[u], b_[u].z, az);
                aw = fmaf(a_[u], b_[u].w, aw);
                qacc = fmaf(a_[u], a_[u], qacc);
            }
        }
        for (; ee < nb; ++ee) {
            int rb = __builtin_amdgcn_readlane(rx, ee);
            int cb = __builtin_amdgcn_readlane(cx, ee);
            float a = sel[rb + i];
            float4 bv = *(const float4*)(sel + cb + j0);
            ax = fmaf(a, bv.x, ax);
            ay = fmaf(a, bv.y, ay);
            az = fmaf(a, bv.z, az);
            aw = fmaf(a, bv.w, aw);
            qacc = fmaf(a, a, qacc);
        }
    }
    __shared__ float lacc[4][256];
    __shared__ float qred[4];
    *(float4*)&lacc[wid][i * K_DIMC + j0] = make_float4(ax, ay, az, aw);
#pragma unroll
    for (int off = 32; off > 0; off >>= 1) qacc += __shfl_down(qacc, off);
    if (lane == 0) qred[wid] = qacc;
    __syncthreads();
    int t = threadIdx.x;
    float s = lacc[0][t] + lacc[1][t] + lacc[2][t] + lacc[3][t];
    atomicAdd(dense_raw + g * 256 + t, s);
    if (t == 0) {
        float qs = (qred[0] + qred[1] + qred[2] + qred[3]) * 0.25f;
        atomicAdd(den + g, qs);
    }
}

// ---- SX/SS standalone (round-7 proven config): grid (SX_SPLIT, NGRAPH), 8 waves ----
__global__ __launch_bounds__(512) void k_sx(const float* __restrict__ sel,
                                            const float* __restrict__ x,
                                            float* __restrict__ ssbuf,
                                            float* __restrict__ sxbuf, int perG) {
    int g = blockIdx.y;
    int wid = threadIdx.x >> 6;
    int wslot = blockIdx.x * SX_WAVES + wid;     // 0..63
    int lane = threadIdx.x & 63;
    int k = lane >> 2;
    int sub = lane & 3;
    int f0 = sub * 16;
    int j0 = sub * 4;
    float accss[4] = {0.f, 0.f, 0.f, 0.f};
    float accsx[16];
#pragma unroll
    for (int j = 0; j < 16; ++j) accsx[j] = 0.f;
    size_t base = (size_t)g * perG;
    int stride = SX_SPLIT * SX_WAVES;            // 64
#pragma unroll 2
    for (int nn = wslot; nn < perG; nn += stride) {
        size_t node = base + nn;
        float a = sel[node * K_DIMC + k];
        float4 s4 = *(const float4*)(sel + node * K_DIMC + j0);
        accss[0] += a * s4.x;
        accss[1] += a * s4.y;
        accss[2] += a * s4.z;
        accss[3] += a * s4.w;
        const float4* xv = (const float4*)(x + node * F_DIMC + f0);
#pragma unroll
        for (int j = 0; j < 4; ++j) {
            float4 v = xv[j];
            accsx[4 * j + 0] += a * v.x;
            accsx[4 * j + 1] += a * v.y;
            accsx[4 * j + 2] += a * v.z;
            accsx[4 * j + 3] += a * v.w;
        }
    }
    __shared__ float lsx[SX_WAVES][K_DIMC * F_DIMC];  // 32 KB
    __shared__ float lss[SX_WAVES][256];              // 8 KB
#pragma unroll
    for (int j4 = 0; j4 < 4; ++j4) {
        *(float4*)&lsx[wid][k * F_DIMC + f0 + 4 * j4] =
            make_float4(accsx[4 * j4], accsx[4 * j4 + 1], accsx[4 * j4 + 2], accsx[4 * j4 + 3]);
    }
    *(float4*)&lss[wid][k * K_DIMC + j0] = make_float4(accss[0], accss[1], accss[2], accss[3]);
    __syncthreads();
    for (int c = threadIdx.x; c < K_DIMC * F_DIMC; c += 512) {
        float s = 0.f;
#pragma unroll
        for (int w = 0; w < SX_WAVES; ++w) s += lsx[w][c];
        atomicAdd(sxbuf + (size_t)g * (K_DIMC * F_DIMC) + c, s);
    }
    if (threadIdx.x < 256) {
        int c = threadIdx.x;
        float s = 0.f;
#pragma unroll
        for (int w = 0; w < SX_WAVES; ++w) s += lss[w][c];
        atomicAdd(ssbuf + g * 256 + c, s);
    }
}

// ---- finalize: normalize adj, copy SX to out, losses via ws + last-block write ----
__global__ __launch_bounds__(256) void k_fin(const float* __restrict__ dense_raw,
                                             const float* __restrict__ ssbuf,
                                             const float* __restrict__ sxbuf,
                                             const float* __restrict__ den,
                                             float* __restrict__ lossws,
                                             int* __restrict__ donecnt,
                                             float* __restrict__ out) {
    int g = blockIdx.x;
    int c = threadIdx.x;
    int k = c >> 4, j = c & 15;
    int lane = threadIdx.x & 63;
    int wid = threadIdx.x >> 6;

    ((float4*)(out + (size_t)g * (K_DIMC * F_DIMC)))[c] =
        ((const float4*)(sxbuf + (size_t)g * (K_DIMC * F_DIMC)))[c];

    float a = dense_raw[g * 256 + c];
    float s = a;
    s += __shfl_xor(s, 1);
    s += __shfl_xor(s, 2);
    s += __shfl_xor(s, 4);
    s += __shfl_xor(s, 8);
    __shared__ float dvrow[K_DIMC];
    if (j == 0) dvrow[k] = sqrtf(s) + 1e-15f;
    __syncthreads();
    float v = a / (dvrow[k] * dvrow[j]);
    out[ADJ_OFF + g * 256 + c] = v;

    float ss = ssbuf[g * 256 + c];
    float tt = (k == j) ? v : 0.f;
    float n2 = ss * ss;
#pragma unroll
    for (int off = 32; off > 0; off >>= 1) {
        tt += __shfl_down(tt, off);
        n2 += __shfl_down(n2, off);
    }
    __shared__ float redt[4], redn[4];
    if (lane == 0) { redt[wid] = tt; redn[wid] = n2; }
    __syncthreads();
    float tr = redt[0] + redt[1] + redt[2] + redt[3];
    float nrm2 = redn[0] + redn[1] + redn[2] + redn[3];
    float invn = 1.f / sqrtf(nrm2);
    float d = ss * invn - ((k == j) ? 0.25f : 0.f);
    float o2 = d * d;
#pragma unroll
    for (int off = 32; off > 0; off >>= 1) o2 += __shfl_down(o2, off);
    __shared__ float redo[4];
    if (lane == 0) redo[wid] = o2;
    __syncthreads();
    if (threadIdx.x == 0) {
        float osum = redo[0] + redo[1] + redo[2] + redo[3];
        float og = sqrtf(osum);
        float mterm = -(tr / den[g]);
        atomicAdd(lossws + 0, mterm * (1.f / NGRAPH));
        atomicAdd(lossws + 1, og * (1.f / NGRAPH));
        __threadfence();
        int old = atomicAdd(donecnt, 1);
        if (old == NGRAPH - 1) {
            float l0 = atomicAdd(lossws + 0, 0.f);
            float l1 = atomicAdd(lossws + 1, 0.f);
            out[LOSS_OFF + 0] = l0;
            out[LOSS_OFF + 1] = l1;
        }
    }
}

extern "C" void kernel_launch(void* const* d_in, const int* in_sizes, int n_in,
                              void* d_out, int out_size, void* d_ws, size_t ws_size,
                              hipStream_t stream) {
    const float* node_attr = (const float*)d_in[0];
    const float* W = (const float*)d_in[1];
    const float* bias = (const float*)d_in[2];
    const int* edge_index = (const int*)d_in[3];
    int N = in_sizes[0] / F_DIMC;
    int E = in_sizes[3] / 2;
    int perG = N / NGRAPH;
    const int* row = edge_index;
    const int* col = edge_index + E;
    float* out = (float*)d_out;
    char* ws = (char*)d_ws;

    int* hist = (int*)(ws + 0);
    int* cursor = (int*)(ws + 256);
    float* den = (float*)(ws + 512);
    int* donecnt = (int*)(ws + 768);
    float* dense_raw = (float*)(ws + 1024);
    float* ssbuf = (float*)(ws + 66560);
    float* sxbuf = (float*)(ws + 132096);
    float* lossws = (float*)(ws + 394240);
    int* offsets = (int*)(ws + 394496);
    float* sel = (float*)(ws + 394752);
    uint2* sorted = (uint2*)(ws + 6948352);

    hipMemsetAsync(ws, 0, 394496, stream);

    k_hist<<<NB_HIST, 256, 0, stream>>>(row, hist, E / 4, perG);
    k_sel_scatter<<<NB_SEL + (E + 255) / 256, 256, 0, stream>>>(node_attr, W, bias, row, col,
                                                                hist, cursor, offsets, sel,
                                                                sorted, N, E, perG);
    k_adj<<<ADJ_SPLIT * NGRAPH, 256, 0, stream>>>(sorted, offsets, hist, sel, dense_raw, den);
    k_sx<<<dim3(SX_SPLIT, NGRAPH), 512, 0, stream>>>(sel, node_attr, ssbuf, sxbuf, perG);
    k_fin<<<NGRAPH, 256, 0, stream>>>(dense_raw, ssbuf, sxbuf, den, lossws, donecnt, out);
}

// Round 12
// 106.020 us; speedup vs baseline: 2.0853x; 1.4327x over previous
//
#include <hip/hip_runtime.h>

#define F_DIMC 64
#define K_DIMC 16
#define NGRAPH 64
#define NXCD 8
#define ADJ_SPLIT 32
#define SX_WAVES 8
#define SX_SPLIT 8
#define NB_SEL 400                         // N/256
#define NB_CHUNK 256                       // histogram/scatter chunks
#define CHUNK_I4 800                       // int4s per chunk (256*800 = E/4)
#define ADJ_OFF (NGRAPH * K_DIMC * F_DIMC)
#define LOSS_OFF (ADJ_OFF + NGRAPH * K_DIMC * K_DIMC)

// ---------------- workspace layout (bytes) ----------------
// zeroed each call: [0, 394240)
//   [0,256)          den (float[64])
//   [256,512)        donecnt (int) + pad
//   [512,768)        lossws (float[2]) + pad
//   [768,1024)       pad
//   [1024,66560)     dense_raw (float[64*256])
//   [66560,132096)   ssbuf (float[64*256])
//   [132096,394240)  sxbuf (float[64*1024])
// not zeroed:
//   [394240,394496)    offsets (int[64])       (scatter block 0 writes)
//   [394496,394752)    gtot (int[64])          (chunkscan writes)
//   [394752,460288)    blockhist (int[256][64])
//   [460288,525824)    chunkbase (int[256][64])
//   [525824,7079424)   sel (float[N*16])
//   [7079424,13633024) sorted (uint2[E])

// ---- fused: selection (blocks [0,NB_SEL)) || per-chunk histogram (rest) ----
__global__ __launch_bounds__(256) void k_sel_hist(const float* __restrict__ node_attr,
                                                  const float* __restrict__ W,
                                                  const float* __restrict__ bias,
                                                  const int* __restrict__ row,
                                                  float* __restrict__ sel,
                                                  int* __restrict__ blockhist,
                                                  int N, int perG) {
    int t = threadIdx.x;
    if (blockIdx.x < NB_SEL) {
        __shared__ float sW[K_DIMC][F_DIMC];
        __shared__ float sb[K_DIMC];
        for (int idx = t; idx < F_DIMC * K_DIMC; idx += 256) {
            int f = idx / K_DIMC, k = idx % K_DIMC;
            sW[k][f] = W[idx];
        }
        if (t < K_DIMC) sb[t] = bias[t];
        __syncthreads();
        int n = blockIdx.x * 256 + t;
        if (n >= N) return;

        const float4* xr = (const float4*)(node_attr + (size_t)n * F_DIMC);
        float4 x[F_DIMC / 4];
#pragma unroll
        for (int f4 = 0; f4 < F_DIMC / 4; ++f4) x[f4] = xr[f4];

        float logits[K_DIMC];
#pragma unroll
        for (int k = 0; k < K_DIMC; ++k) {
            const float4* wk = (const float4*)&sW[k][0];
            float acc = sb[k];
#pragma unroll
            for (int f4 = 0; f4 < F_DIMC / 4; ++f4) {
                float4 w = wk[f4];
                acc += x[f4].x * w.x + x[f4].y * w.y + x[f4].z * w.z + x[f4].w * w.w;
            }
            logits[k] = acc;
        }
        float m = logits[0];
#pragma unroll
        for (int k = 1; k < K_DIMC; ++k) m = fmaxf(m, logits[k]);
        float sum = 0.f;
#pragma unroll
        for (int k = 0; k < K_DIMC; ++k) {
            float e = __expf(logits[k] - m);
            logits[k] = e;
            sum += e;
        }
        float inv = 1.f / sum;
        float4* sd = (float4*)(sel + (size_t)n * K_DIMC);
#pragma unroll
        for (int k4 = 0; k4 < K_DIMC / 4; ++k4) {
            float4 v;
            v.x = logits[4 * k4 + 0] * inv;
            v.y = logits[4 * k4 + 1] * inv;
            v.z = logits[4 * k4 + 2] * inv;
            v.w = logits[4 * k4 + 3] * inv;
            sd[k4] = v;
        }
    } else {
        __shared__ int lh[NGRAPH];
        int h = blockIdx.x - NB_SEL;                 // 0..255, static chunk
        if (t < NGRAPH) lh[t] = 0;
        __syncthreads();
        for (int i = t; i < CHUNK_I4; i += 256) {
            int4 r4 = ((const int4*)row)[h * CHUNK_I4 + i];
            atomicAdd(&lh[r4.x / perG], 1);
            atomicAdd(&lh[r4.y / perG], 1);
            atomicAdd(&lh[r4.z / perG], 1);
            atomicAdd(&lh[r4.w / perG], 1);
        }
        __syncthreads();
        if (t < NGRAPH) blockhist[h * NGRAPH + t] = lh[t];
    }
}

// ---- per-graph exclusive scan over 256 chunks: chunkbase[b][g], gtot[g] ----
__global__ __launch_bounds__(256) void k_chunkscan(const int* __restrict__ blockhist,
                                                   int* __restrict__ chunkbase,
                                                   int* __restrict__ gtot) {
    int g = blockIdx.x;
    int t = threadIdx.x;                 // 0..255 = chunk index
    int lane = t & 63;
    int wid = t >> 6;
    int v = blockhist[t * NGRAPH + g];
    int s = v;
#pragma unroll
    for (int d = 1; d < 64; d <<= 1) {
        int o = __shfl_up(s, d);
        if (lane >= d) s += o;
    }
    __shared__ int wsum[4];
    if (lane == 63) wsum[wid] = s;
    __syncthreads();
    int pre = 0;
#pragma unroll
    for (int w = 0; w < 4; ++w) pre += (w < wid) ? wsum[w] : 0;
    int incl = s + pre;
    chunkbase[t * NGRAPH + g] = incl - v;
    if (t == 255) gtot[g] = incl;
}

// ---- deterministic scatter: same static chunks; LDS position counters only ----
__global__ __launch_bounds__(256) void k_scatter(const int* __restrict__ row,
                                                 const int* __restrict__ col,
                                                 const int* __restrict__ gtot,
                                                 const int* __restrict__ chunkbase,
                                                 int* __restrict__ offsets,
                                                 uint2* __restrict__ sorted,
                                                 int perG) {
    __shared__ int base_[NGRAPH];
    __shared__ int lcnt[NGRAPH];
    int t = threadIdx.x;
    int h = blockIdx.x;                  // 0..255, same chunk as hist
    if (t < 64) {
        int v = gtot[t];
        int s = v;
#pragma unroll
        for (int d = 1; d < 64; d <<= 1) {
            int o = __shfl_up(s, d);
            if (t >= d) s += o;
        }
        int offs = s - v;                // exclusive scan = graph base
        base_[t] = offs + chunkbase[h * NGRAPH + t];
        lcnt[t] = 0;
        if (h == 0) offsets[t] = offs;
    }
    __syncthreads();
    for (int i = t; i < CHUNK_I4; i += 256) {
        int e4 = h * CHUNK_I4 + i;
        int4 r4 = ((const int4*)row)[e4];
        int4 c4 = ((const int4*)col)[e4];
        int rr[4] = {r4.x, r4.y, r4.z, r4.w};
        int cc[4] = {c4.x, c4.y, c4.z, c4.w};
#pragma unroll
        for (int u = 0; u < 4; ++u) {
            int g = rr[u] / perG;
            int lpos = atomicAdd(&lcnt[g], 1);
            sorted[(size_t)base_[g] + lpos] = make_uint2((unsigned)rr[u], (unsigned)cc[u]);
        }
    }
}

// ---- adj: flat 2048 blocks, XCD-swizzled; batched loads + readlane broadcast ----
__global__ __launch_bounds__(256) void k_adj(const uint2* __restrict__ sorted,
                                             const int* __restrict__ offsets,
                                             const int* __restrict__ gtot,
                                             const float* __restrict__ sel,
                                             float* __restrict__ dense_raw,
                                             float* __restrict__ den) {
    int b = blockIdx.x;
    int xcd = b & (NXCD - 1);
    int idx = b >> 3;
    int g = xcd * (NGRAPH / NXCD) + (idx >> 5);
    int split = idx & (ADJ_SPLIT - 1);

    int start = offsets[g];
    int cnt = gtot[g];
    int wavesPerGraph = ADJ_SPLIT * 4;        // 128
    int wid = threadIdx.x >> 6;
    int wseq = split * 4 + wid;
    int lane = threadIdx.x & 63;
    int i = lane >> 2;
    int j0 = (lane & 3) * 4;

    int chunk = (cnt + wavesPerGraph - 1) / wavesPerGraph;
    int myStart = start + wseq * chunk;
    int myEnd = start + cnt;
    if (myStart + chunk < myEnd) myEnd = myStart + chunk;

    float ax = 0.f, ay = 0.f, az = 0.f, aw = 0.f, qacc = 0.f;
    for (int r0 = myStart; r0 < myEnd; r0 += 64) {
        int nb = myEnd - r0;
        if (nb > 64) nb = 64;
        uint2 pr = sorted[r0 + (lane < nb ? lane : nb - 1)];
        int rx = (int)pr.x * K_DIMC;
        int cx = (int)pr.y * K_DIMC;
        int ee = 0;
        for (; ee + 8 <= nb; ee += 8) {
            float a_[8];
            float4 b_[8];
#pragma unroll
            for (int u = 0; u < 8; ++u) {
                int rb = __builtin_amdgcn_readlane(rx, ee + u);
                int cb = __builtin_amdgcn_readlane(cx, ee + u);
                a_[u] = sel[rb + i];
                b_[u] = *(const float4*)(sel + cb + j0);
            }
#pragma unroll
            for (int u = 0; u < 8; ++u) {
                ax = fmaf(a_[u], b_[u].x, ax);
                ay = fmaf(a_[u], b_[u].y, ay);
                az = fmaf(a_[u], b_[u].z, az);
                aw = fmaf(a_[u], b_[u].w, aw);
                qacc = fmaf(a_[u], a_[u], qacc);
            }
        }
        for (; ee < nb; ++ee) {
            int rb = __builtin_amdgcn_readlane(rx, ee);
            int cb = __builtin_amdgcn_readlane(cx, ee);
            float a = sel[rb + i];
            float4 bv = *(const float4*)(sel + cb + j0);
            ax = fmaf(a, bv.x, ax);
            ay = fmaf(a, bv.y, ay);
            az = fmaf(a, bv.z, az);
            aw = fmaf(a, bv.w, aw);
            qacc = fmaf(a, a, qacc);
        }
    }
    __shared__ float lacc[4][256];
    __shared__ float qred[4];
    *(float4*)&lacc[wid][i * K_DIMC + j0] = make_float4(ax, ay, az, aw);
#pragma unroll
    for (int off = 32; off > 0; off >>= 1) qacc += __shfl_down(qacc, off);
    if (lane == 0) qred[wid] = qacc;
    __syncthreads();
    int t = threadIdx.x;
    float s = lacc[0][t] + lacc[1][t] + lacc[2][t] + lacc[3][t];
    atomicAdd(dense_raw + g * 256 + t, s);
    if (t == 0) {
        float qs = (qred[0] + qred[1] + qred[2] + qred[3]) * 0.25f;
        atomicAdd(den + g, qs);
    }
}

// ---- SX/SS: grid (SX_SPLIT, NGRAPH), 8 waves ----
__global__ __launch_bounds__(512) void k_sx(const float* __restrict__ sel,
                                            const float* __restrict__ x,
                                            float* __restrict__ ssbuf,
                                            float* __restrict__ sxbuf, int perG) {
    int g = blockIdx.y;
    int wid = threadIdx.x >> 6;
    int wslot = blockIdx.x * SX_WAVES + wid;     // 0..63
    int lane = threadIdx.x & 63;
    int k = lane >> 2;
    int sub = lane & 3;
    int f0 = sub * 16;
    int j0 = sub * 4;
    float accss[4] = {0.f, 0.f, 0.f, 0.f};
    float accsx[16];
#pragma unroll
    for (int j = 0; j < 16; ++j) accsx[j] = 0.f;
    size_t base = (size_t)g * perG;
    int stride = SX_SPLIT * SX_WAVES;            // 64
#pragma unroll 2
    for (int nn = wslot; nn < perG; nn += stride) {
        size_t node = base + nn;
        float a = sel[node * K_DIMC + k];
        float4 s4 = *(const float4*)(sel + node * K_DIMC + j0);
        accss[0] += a * s4.x;
        accss[1] += a * s4.y;
        accss[2] += a * s4.z;
        accss[3] += a * s4.w;
        const float4* xv = (const float4*)(x + node * F_DIMC + f0);
#pragma unroll
        for (int j = 0; j < 4; ++j) {
            float4 v = xv[j];
            accsx[4 * j + 0] += a * v.x;
            accsx[4 * j + 1] += a * v.y;
            accsx[4 * j + 2] += a * v.z;
            accsx[4 * j + 3] += a * v.w;
        }
    }
    __shared__ float lsx[SX_WAVES][K_DIMC * F_DIMC];  // 32 KB
    __shared__ float lss[SX_WAVES][256];              // 8 KB
#pragma unroll
    for (int j4 = 0; j4 < 4; ++j4) {
        *(float4*)&lsx[wid][k * F_DIMC + f0 + 4 * j4] =
            make_float4(accsx[4 * j4], accsx[4 * j4 + 1], accsx[4 * j4 + 2], accsx[4 * j4 + 3]);
    }
    *(float4*)&lss[wid][k * K_DIMC + j0] = make_float4(accss[0], accss[1], accss[2], accss[3]);
    __syncthreads();
    for (int c = threadIdx.x; c < K_DIMC * F_DIMC; c += 512) {
        float s = 0.f;
#pragma unroll
        for (int w = 0; w < SX_WAVES; ++w) s += lsx[w][c];
        atomicAdd(sxbuf + (size_t)g * (K_DIMC * F_DIMC) + c, s);
    }
    if (threadIdx.x < 256) {
        int c = threadIdx.x;
        float s = 0.f;
#pragma unroll
        for (int w = 0; w < SX_WAVES; ++w) s += lss[w][c];
        atomicAdd(ssbuf + g * 256 + c, s);
    }
}

// ---- finalize: normalize adj, copy SX to out, losses via ws + last-block write ----
__global__ __launch_bounds__(256) void k_fin(const float* __restrict__ dense_raw,
                                             const float* __restrict__ ssbuf,
                                             const float* __restrict__ sxbuf,
                                             const float* __restrict__ den,
                                             float* __restrict__ lossws,
                                             int* __restrict__ donecnt,
                                             float* __restrict__ out) {
    int g = blockIdx.x;
    int c = threadIdx.x;
    int k = c >> 4, j = c & 15;
    int lane = threadIdx.x & 63;
    int wid = threadIdx.x >> 6;

    ((float4*)(out + (size_t)g * (K_DIMC * F_DIMC)))[c] =
        ((const float4*)(sxbuf + (size_t)g * (K_DIMC * F_DIMC)))[c];

    float a = dense_raw[g * 256 + c];
    float s = a;
    s += __shfl_xor(s, 1);
    s += __shfl_xor(s, 2);
    s += __shfl_xor(s, 4);
    s += __shfl_xor(s, 8);
    __shared__ float dvrow[K_DIMC];
    if (j == 0) dvrow[k] = sqrtf(s) + 1e-15f;
    __syncthreads();
    float v = a / (dvrow[k] * dvrow[j]);
    out[ADJ_OFF + g * 256 + c] = v;

    float ss = ssbuf[g * 256 + c];
    float tt = (k == j) ? v : 0.f;
    float n2 = ss * ss;
#pragma unroll
    for (int off = 32; off > 0; off >>= 1) {
        tt += __shfl_down(tt, off);
        n2 += __shfl_down(n2, off);
    }
    __shared__ float redt[4], redn[4];
    if (lane == 0) { redt[wid] = tt; redn[wid] = n2; }
    __syncthreads();
    float tr = redt[0] + redt[1] + redt[2] + redt[3];
    float nrm2 = redn[0] + redn[1] + redn[2] + redn[3];
    float invn = 1.f / sqrtf(nrm2);
    float d = ss * invn - ((k == j) ? 0.25f : 0.f);
    float o2 = d * d;
#pragma unroll
    for (int off = 32; off > 0; off >>= 1) o2 += __shfl_down(o2, off);
    __shared__ float redo[4];
    if (lane == 0) redo[wid] = o2;
    __syncthreads();
    if (threadIdx.x == 0) {
        float osum = redo[0] + redo[1] + redo[2] + redo[3];
        float og = sqrtf(osum);
        float mterm = -(tr / den[g]);
        atomicAdd(lossws + 0, mterm * (1.f / NGRAPH));
        atomicAdd(lossws + 1, og * (1.f / NGRAPH));
        __threadfence();
        int old = atomicAdd(donecnt, 1);
        if (old == NGRAPH - 1) {
            float l0 = atomicAdd(lossws + 0, 0.f);
            float l1 = atomicAdd(lossws + 1, 0.f);
            out[LOSS_OFF + 0] = l0;
            out[LOSS_OFF + 1] = l1;
        }
    }
}

extern "C" void kernel_launch(void* const* d_in, const int* in_sizes, int n_in,
                              void* d_out, int out_size, void* d_ws, size_t ws_size,
                              hipStream_t stream) {
    const float* node_attr = (const float*)d_in[0];
    const float* W = (const float*)d_in[1];
    const float* bias = (const float*)d_in[2];
    const int* edge_index = (const int*)d_in[3];
    int N = in_sizes[0] / F_DIMC;
    int E = in_sizes[3] / 2;
    int perG = N / NGRAPH;
    const int* row = edge_index;
    const int* col = edge_index + E;
    float* out = (float*)d_out;
    char* ws = (char*)d_ws;

    float* den = (float*)(ws + 0);
    int* donecnt = (int*)(ws + 256);
    float* lossws = (float*)(ws + 512);
    float* dense_raw = (float*)(ws + 1024);
    float* ssbuf = (float*)(ws + 66560);
    float* sxbuf = (float*)(ws + 132096);
    int* offsets = (int*)(ws + 394240);
    int* gtot = (int*)(ws + 394496);
    int* blockhist = (int*)(ws + 394752);
    int* chunkbase = (int*)(ws + 460288);
    float* sel = (float*)(ws + 525824);
    uint2* sorted = (uint2*)(ws + 7079424);

    hipMemsetAsync(ws, 0, 394240, stream);

    k_sel_hist<<<NB_SEL + NB_CHUNK, 256, 0, stream>>>(node_attr, W, bias, row, sel,
                                                      blockhist, N, perG);
    k_chunkscan<<<NGRAPH, 256, 0, stream>>>(blockhist, chunkbase, gtot);
    k_scatter<<<NB_CHUNK, 256, 0, stream>>>(row, col, gtot, chunkbase, offsets,
                                            sorted, perG);
    k_adj<<<ADJ_SPLIT * NGRAPH, 256, 0, stream>>>(sorted, offsets, gtot, sel, dense_raw, den);
    k_sx<<<dim3(SX_SPLIT, NGRAPH), 512, 0, stream>>>(sel, node_attr, ssbuf, sxbuf, perG);
    k_fin<<<NGRAPH, 256, 0, stream>>>(dense_raw, ssbuf, sxbuf, den, lossws, donecnt, out);
}

// Round 13
// 105.264 us; speedup vs baseline: 2.1003x; 1.0072x over previous
//
#include <hip/hip_runtime.h>

#define F_DIMC 64
#define K_DIMC 16
#define NGRAPH 64
#define NXCD 8
#define ADJ_SPLIT 32
#define SX_WAVES 8
#define SX_SPLIT 8
#define NB_SEL 400                         // N/256
#define NB_CHUNK 256                       // histogram/scatter chunks
#define CHUNK_I4 800                       // int4s per chunk (256*800 = E/4)
#define ADJ_OFF (NGRAPH * K_DIMC * F_DIMC)
#define LOSS_OFF (ADJ_OFF + NGRAPH * K_DIMC * K_DIMC)
#define ZERO_BYTES 394240

// ---------------- workspace layout (bytes) ----------------
// zeroed each call by k_zero: [0, 394240)
//   [0,256)          den (float[64])
//   [256,512)        donecnt (int) + pad
//   [512,768)        lossws (float[2]) + pad
//   [768,1024)       pad
//   [1024,66560)     dense_raw (float[64*256])
//   [66560,132096)   ssbuf (float[64*256])
//   [132096,394240)  sxbuf (float[64*1024])
// not zeroed:
//   [394240,394496)    offsets (int[64])       (scatter block 0 writes)
//   [394496,394752)    gtot (int[64])          (chunkscan writes)
//   [394752,460288)    blockhist (int[256][64])
//   [460288,525824)    chunkbase (int[256][64])
//   [525824,7079424)   sel (float[N*16])
//   [7079424,13633024) sorted (uint2[E])

// runtime fillBuffer costs ~40us/dispatch regardless of size -> zero ws ourselves
__global__ __launch_bounds__(256) void k_zero(float4* __restrict__ p, int n4) {
    int i = blockIdx.x * 256 + threadIdx.x;
    int stride = gridDim.x * 256;
    for (; i < n4; i += stride) p[i] = make_float4(0.f, 0.f, 0.f, 0.f);
}

// ---- fused: selection (blocks [0,NB_SEL)) || per-chunk histogram (rest) ----
__global__ __launch_bounds__(256) void k_sel_hist(const float* __restrict__ node_attr,
                                                  const float* __restrict__ W,
                                                  const float* __restrict__ bias,
                                                  const int* __restrict__ row,
                                                  float* __restrict__ sel,
                                                  int* __restrict__ blockhist,
                                                  int N, int perG) {
    int t = threadIdx.x;
    if (blockIdx.x < NB_SEL) {
        __shared__ float sW[K_DIMC][F_DIMC];
        __shared__ float sb[K_DIMC];
        for (int idx = t; idx < F_DIMC * K_DIMC; idx += 256) {
            int f = idx / K_DIMC, k = idx % K_DIMC;
            sW[k][f] = W[idx];
        }
        if (t < K_DIMC) sb[t] = bias[t];
        __syncthreads();
        int n = blockIdx.x * 256 + t;
        if (n >= N) return;

        const float4* xr = (const float4*)(node_attr + (size_t)n * F_DIMC);
        float4 x[F_DIMC / 4];
#pragma unroll
        for (int f4 = 0; f4 < F_DIMC / 4; ++f4) x[f4] = xr[f4];

        float logits[K_DIMC];
#pragma unroll
        for (int k = 0; k < K_DIMC; ++k) {
            const float4* wk = (const float4*)&sW[k][0];
            float acc = sb[k];
#pragma unroll
            for (int f4 = 0; f4 < F_DIMC / 4; ++f4) {
                float4 w = wk[f4];
                acc += x[f4].x * w.x + x[f4].y * w.y + x[f4].z * w.z + x[f4].w * w.w;
            }
            logits[k] = acc;
        }
        float m = logits[0];
#pragma unroll
        for (int k = 1; k < K_DIMC; ++k) m = fmaxf(m, logits[k]);
        float sum = 0.f;
#pragma unroll
        for (int k = 0; k < K_DIMC; ++k) {
            float e = __expf(logits[k] - m);
            logits[k] = e;
            sum += e;
        }
        float inv = 1.f / sum;
        float4* sd = (float4*)(sel + (size_t)n * K_DIMC);
#pragma unroll
        for (int k4 = 0; k4 < K_DIMC / 4; ++k4) {
            float4 v;
            v.x = logits[4 * k4 + 0] * inv;
            v.y = logits[4 * k4 + 1] * inv;
            v.z = logits[4 * k4 + 2] * inv;
            v.w = logits[4 * k4 + 3] * inv;
            sd[k4] = v;
        }
    } else {
        __shared__ int lh[NGRAPH];
        int h = blockIdx.x - NB_SEL;                 // 0..255, static chunk
        if (t < NGRAPH) lh[t] = 0;
        __syncthreads();
        for (int i = t; i < CHUNK_I4; i += 256) {
            int4 r4 = ((const int4*)row)[h * CHUNK_I4 + i];
            atomicAdd(&lh[r4.x / perG], 1);
            atomicAdd(&lh[r4.y / perG], 1);
            atomicAdd(&lh[r4.z / perG], 1);
            atomicAdd(&lh[r4.w / perG], 1);
        }
        __syncthreads();
        if (t < NGRAPH) blockhist[h * NGRAPH + t] = lh[t];
    }
}

// ---- per-graph exclusive scan over 256 chunks: chunkbase[b][g], gtot[g] ----
__global__ __launch_bounds__(256) void k_chunkscan(const int* __restrict__ blockhist,
                                                   int* __restrict__ chunkbase,
                                                   int* __restrict__ gtot) {
    int g = blockIdx.x;
    int t = threadIdx.x;                 // 0..255 = chunk index
    int lane = t & 63;
    int wid = t >> 6;
    int v = blockhist[t * NGRAPH + g];
    int s = v;
#pragma unroll
    for (int d = 1; d < 64; d <<= 1) {
        int o = __shfl_up(s, d);
        if (lane >= d) s += o;
    }
    __shared__ int wsum[4];
    if (lane == 63) wsum[wid] = s;
    __syncthreads();
    int pre = 0;
#pragma unroll
    for (int w = 0; w < 4; ++w) pre += (w < wid) ? wsum[w] : 0;
    int incl = s + pre;
    chunkbase[t * NGRAPH + g] = incl - v;
    if (t == 255) gtot[g] = incl;
}

// ---- deterministic scatter: same static chunks; LDS position counters only ----
__global__ __launch_bounds__(256) void k_scatter(const int* __restrict__ row,
                                                 const int* __restrict__ col,
                                                 const int* __restrict__ gtot,
                                                 const int* __restrict__ chunkbase,
                                                 int* __restrict__ offsets,
                                                 uint2* __restrict__ sorted,
                                                 int perG) {
    __shared__ int base_[NGRAPH];
    __shared__ int lcnt[NGRAPH];
    int t = threadIdx.x;
    int h = blockIdx.x;                  // 0..255, same chunk as hist
    if (t < 64) {
        int v = gtot[t];
        int s = v;
#pragma unroll
        for (int d = 1; d < 64; d <<= 1) {
            int o = __shfl_up(s, d);
            if (t >= d) s += o;
        }
        int offs = s - v;                // exclusive scan = graph base
        base_[t] = offs + chunkbase[h * NGRAPH + t];
        lcnt[t] = 0;
        if (h == 0) offsets[t] = offs;
    }
    __syncthreads();
    for (int i = t; i < CHUNK_I4; i += 256) {
        int e4 = h * CHUNK_I4 + i;
        int4 r4 = ((const int4*)row)[e4];
        int4 c4 = ((const int4*)col)[e4];
        int rr[4] = {r4.x, r4.y, r4.z, r4.w};
        int cc[4] = {c4.x, c4.y, c4.z, c4.w};
#pragma unroll
        for (int u = 0; u < 4; ++u) {
            int g = rr[u] / perG;
            int lpos = atomicAdd(&lcnt[g], 1);
            sorted[(size_t)base_[g] + lpos] = make_uint2((unsigned)rr[u], (unsigned)cc[u]);
        }
    }
}

// ---- adj: flat 2048 blocks, XCD-swizzled; batched loads + readlane broadcast.
// Even/odd 4-edge subgroups accumulate into TWO independent register sets
// (merged at the end) -> two independent load/FMA streams, half the chain length.
__global__ __launch_bounds__(256) void k_adj(const uint2* __restrict__ sorted,
                                             const int* __restrict__ offsets,
                                             const int* __restrict__ gtot,
                                             const float* __restrict__ sel,
                                             float* __restrict__ dense_raw,
                                             float* __restrict__ den) {
    int b = blockIdx.x;
    int xcd = b & (NXCD - 1);
    int idx = b >> 3;
    int g = xcd * (NGRAPH / NXCD) + (idx >> 5);
    int split = idx & (ADJ_SPLIT - 1);

    int start = offsets[g];
    int cnt = gtot[g];
    int wavesPerGraph = ADJ_SPLIT * 4;        // 128
    int wid = threadIdx.x >> 6;
    int wseq = split * 4 + wid;
    int lane = threadIdx.x & 63;
    int i = lane >> 2;
    int j0 = (lane & 3) * 4;

    int chunk = (cnt + wavesPerGraph - 1) / wavesPerGraph;
    int myStart = start + wseq * chunk;
    int myEnd = start + cnt;
    if (myStart + chunk < myEnd) myEnd = myStart + chunk;

    float ax0 = 0.f, ay0 = 0.f, az0 = 0.f, aw0 = 0.f, q0 = 0.f;
    float ax1 = 0.f, ay1 = 0.f, az1 = 0.f, aw1 = 0.f, q1 = 0.f;
    for (int r0 = myStart; r0 < myEnd; r0 += 64) {
        int nb = myEnd - r0;
        if (nb > 64) nb = 64;
        uint2 pr = sorted[r0 + (lane < nb ? lane : nb - 1)];
        int rx = (int)pr.x * K_DIMC;
        int cx = (int)pr.y * K_DIMC;
        int ee = 0;
        for (; ee + 8 <= nb; ee += 8) {
            float a0_[4], a1_[4];
            float4 b0_[4], b1_[4];
#pragma unroll
            for (int u = 0; u < 4; ++u) {
                int rb0 = __builtin_amdgcn_readlane(rx, ee + u);
                int cb0 = __builtin_amdgcn_readlane(cx, ee + u);
                int rb1 = __builtin_amdgcn_readlane(rx, ee + 4 + u);
                int cb1 = __builtin_amdgcn_readlane(cx, ee + 4 + u);
                a0_[u] = sel[rb0 + i];
                b0_[u] = *(const float4*)(sel + cb0 + j0);
                a1_[u] = sel[rb1 + i];
                b1_[u] = *(const float4*)(sel + cb1 + j0);
            }
#pragma unroll
            for (int u = 0; u < 4; ++u) {
                ax0 = fmaf(a0_[u], b0_[u].x, ax0);
                ay0 = fmaf(a0_[u], b0_[u].y, ay0);
                az0 = fmaf(a0_[u], b0_[u].z, az0);
                aw0 = fmaf(a0_[u], b0_[u].w, aw0);
                q0 = fmaf(a0_[u], a0_[u], q0);
                ax1 = fmaf(a1_[u], b1_[u].x, ax1);
                ay1 = fmaf(a1_[u], b1_[u].y, ay1);
                az1 = fmaf(a1_[u], b1_[u].z, az1);
                aw1 = fmaf(a1_[u], b1_[u].w, aw1);
                q1 = fmaf(a1_[u], a1_[u], q1);
            }
        }
        for (; ee < nb; ++ee) {
            int rb = __builtin_amdgcn_readlane(rx, ee);
            int cb = __builtin_amdgcn_readlane(cx, ee);
            float a = sel[rb + i];
            float4 bv = *(const float4*)(sel + cb + j0);
            ax0 = fmaf(a, bv.x, ax0);
            ay0 = fmaf(a, bv.y, ay0);
            az0 = fmaf(a, bv.z, az0);
            aw0 = fmaf(a, bv.w, aw0);
            q0 = fmaf(a, a, q0);
        }
    }
    float ax = ax0 + ax1, ay = ay0 + ay1, az = az0 + az1, aw = aw0 + aw1;
    float qacc = q0 + q1;
    __shared__ float lacc[4][256];
    __shared__ float qred[4];
    *(float4*)&lacc[wid][i * K_DIMC + j0] = make_float4(ax, ay, az, aw);
#pragma unroll
    for (int off = 32; off > 0; off >>= 1) qacc += __shfl_down(qacc, off);
    if (lane == 0) qred[wid] = qacc;
    __syncthreads();
    int t = threadIdx.x;
    float s = lacc[0][t] + lacc[1][t] + lacc[2][t] + lacc[3][t];
    atomicAdd(dense_raw + g * 256 + t, s);
    if (t == 0) {
        float qs = (qred[0] + qred[1] + qred[2] + qred[3]) * 0.25f;
        atomicAdd(den + g, qs);
    }
}

// ---- SX/SS: grid (SX_SPLIT, NGRAPH), 8 waves ----
__global__ __launch_bounds__(512) void k_sx(const float* __restrict__ sel,
                                            const float* __restrict__ x,
                                            float* __restrict__ ssbuf,
                                            float* __restrict__ sxbuf, int perG) {
    int g = blockIdx.y;
    int wid = threadIdx.x >> 6;
    int wslot = blockIdx.x * SX_WAVES + wid;     // 0..63
    int lane = threadIdx.x & 63;
    int k = lane >> 2;
    int sub = lane & 3;
    int f0 = sub * 16;
    int j0 = sub * 4;
    float accss[4] = {0.f, 0.f, 0.f, 0.f};
    float accsx[16];
#pragma unroll
    for (int j = 0; j < 16; ++j) accsx[j] = 0.f;
    size_t base = (size_t)g * perG;
    int stride = SX_SPLIT * SX_WAVES;            // 64
#pragma unroll 2
    for (int nn = wslot; nn < perG; nn += stride) {
        size_t node = base + nn;
        float a = sel[node * K_DIMC + k];
        float4 s4 = *(const float4*)(sel + node * K_DIMC + j0);
        accss[0] += a * s4.x;
        accss[1] += a * s4.y;
        accss[2] += a * s4.z;
        accss[3] += a * s4.w;
        const float4* xv = (const float4*)(x + node * F_DIMC + f0);
#pragma unroll
        for (int j = 0; j < 4; ++j) {
            float4 v = xv[j];
            accsx[4 * j + 0] += a * v.x;
            accsx[4 * j + 1] += a * v.y;
            accsx[4 * j + 2] += a * v.z;
            accsx[4 * j + 3] += a * v.w;
        }
    }
    __shared__ float lsx[SX_WAVES][K_DIMC * F_DIMC];  // 32 KB
    __shared__ float lss[SX_WAVES][256];              // 8 KB
#pragma unroll
    for (int j4 = 0; j4 < 4; ++j4) {
        *(float4*)&lsx[wid][k * F_DIMC + f0 + 4 * j4] =
            make_float4(accsx[4 * j4], accsx[4 * j4 + 1], accsx[4 * j4 + 2], accsx[4 * j4 + 3]);
    }
    *(float4*)&lss[wid][k * K_DIMC + j0] = make_float4(accss[0], accss[1], accss[2], accss[3]);
    __syncthreads();
    for (int c = threadIdx.x; c < K_DIMC * F_DIMC; c += 512) {
        float s = 0.f;
#pragma unroll
        for (int w = 0; w < SX_WAVES; ++w) s += lsx[w][c];
        atomicAdd(sxbuf + (size_t)g * (K_DIMC * F_DIMC) + c, s);
    }
    if (threadIdx.x < 256) {
        int c = threadIdx.x;
        float s = 0.f;
#pragma unroll
        for (int w = 0; w < SX_WAVES; ++w) s += lss[w][c];
        atomicAdd(ssbuf + g * 256 + c, s);
    }
}

// ---- finalize: normalize adj, copy SX to out, losses via ws + last-block write ----
__global__ __launch_bounds__(256) void k_fin(const float* __restrict__ dense_raw,
                                             const float* __restrict__ ssbuf,
                                             const float* __restrict__ sxbuf,
                                             const float* __restrict__ den,
                                             float* __restrict__ lossws,
                                             int* __restrict__ donecnt,
                                             float* __restrict__ out) {
    int g = blockIdx.x;
    int c = threadIdx.x;
    int k = c >> 4, j = c & 15;
    int lane = threadIdx.x & 63;
    int wid = threadIdx.x >> 6;

    ((float4*)(out + (size_t)g * (K_DIMC * F_DIMC)))[c] =
        ((const float4*)(sxbuf + (size_t)g * (K_DIMC * F_DIMC)))[c];

    float a = dense_raw[g * 256 + c];
    float s = a;
    s += __shfl_xor(s, 1);
    s += __shfl_xor(s, 2);
    s += __shfl_xor(s, 4);
    s += __shfl_xor(s, 8);
    __shared__ float dvrow[K_DIMC];
    if (j == 0) dvrow[k] = sqrtf(s) + 1e-15f;
    __syncthreads();
    float v = a / (dvrow[k] * dvrow[j]);
    out[ADJ_OFF + g * 256 + c] = v;

    float ss = ssbuf[g * 256 + c];
    float tt = (k == j) ? v : 0.f;
    float n2 = ss * ss;
#pragma unroll
    for (int off = 32; off > 0; off >>= 1) {
        tt += __shfl_down(tt, off);
        n2 += __shfl_down(n2, off);
    }
    __shared__ float redt[4], redn[4];
    if (lane == 0) { redt[wid] = tt; redn[wid] = n2; }
    __syncthreads();
    float tr = redt[0] + redt[1] + redt[2] + redt[3];
    float nrm2 = redn[0] + redn[1] + redn[2] + redn[3];
    float invn = 1.f / sqrtf(nrm2);
    float d = ss * invn - ((k == j) ? 0.25f : 0.f);
    float o2 = d * d;
#pragma unroll
    for (int off = 32; off > 0; off >>= 1) o2 += __shfl_down(o2, off);
    __shared__ float redo[4];
    if (lane == 0) redo[wid] = o2;
    __syncthreads();
    if (threadIdx.x == 0) {
        float osum = redo[0] + redo[1] + redo[2] + redo[3];
        float og = sqrtf(osum);
        float mterm = -(tr / den[g]);
        atomicAdd(lossws + 0, mterm * (1.f / NGRAPH));
        atomicAdd(lossws + 1, og * (1.f / NGRAPH));
        __threadfence();
        int old = atomicAdd(donecnt, 1);
        if (old == NGRAPH - 1) {
            float l0 = atomicAdd(lossws + 0, 0.f);
            float l1 = atomicAdd(lossws + 1, 0.f);
            out[LOSS_OFF + 0] = l0;
            out[LOSS_OFF + 1] = l1;
        }
    }
}

extern "C" void kernel_launch(void* const* d_in, const int* in_sizes, int n_in,
                              void* d_out, int out_size, void* d_ws, size_t ws_size,
                              hipStream_t stream) {
    const float* node_attr = (const float*)d_in[0];
    const float* W = (const float*)d_in[1];
    const float* bias = (const float*)d_in[2];
    const int* edge_index = (const int*)d_in[3];
    int N = in_sizes[0] / F_DIMC;
    int E = in_sizes[3] / 2;
    int perG = N / NGRAPH;
    const int* row = edge_index;
    const int* col = edge_index + E;
    float* out = (float*)d_out;
    char* ws = (char*)d_ws;

    float* den = (float*)(ws + 0);
    int* donecnt = (int*)(ws + 256);
    float* lossws = (float*)(ws + 512);
    float* dense_raw = (float*)(ws + 1024);
    float* ssbuf = (float*)(ws + 66560);
    float* sxbuf = (float*)(ws + 132096);
    int* offsets = (int*)(ws + 394240);
    int* gtot = (int*)(ws + 394496);
    int* blockhist = (int*)(ws + 394752);
    int* chunkbase = (int*)(ws + 460288);
    float* sel = (float*)(ws + 525824);
    uint2* sorted = (uint2*)(ws + 7079424);

    k_zero<<<64, 256, 0, stream>>>((float4*)ws, ZERO_BYTES / 16);
    k_sel_hist<<<NB_SEL + NB_CHUNK, 256, 0, stream>>>(node_attr, W, bias, row, sel,
                                                      blockhist, N, perG);
    k_chunkscan<<<NGRAPH, 256, 0, stream>>>(blockhist, chunkbase, gtot);
    k_scatter<<<NB_CHUNK, 256, 0, stream>>>(row, col, gtot, chunkbase, offsets,
                                            sorted, perG);
    k_adj<<<ADJ_SPLIT * NGRAPH, 256, 0, stream>>>(sorted, offsets, gtot, sel, dense_raw, den);
    k_sx<<<dim3(SX_SPLIT, NGRAPH), 512, 0, stream>>>(sel, node_attr, ssbuf, sxbuf, perG);
    k_fin<<<NGRAPH, 256, 0, stream>>>(dense_raw, ssbuf, sxbuf, den, lossws, donecnt, out);
}